// Round 1
// baseline (943.715 us; speedup 1.0000x reference)
//
#include <hip/hip_runtime.h>
#include <hip/hip_bf16.h>
#include <type_traits>

#define S_TOK 8192
#define HID 1024
#define INTERX 4096
#define NEXP 8
#define CAPX 1024

using f32x4 = __attribute__((ext_vector_type(4))) float;
using bf16x8 = __attribute__((ext_vector_type(8))) short;

__device__ __forceinline__ short f2bf(float f) {
    union { float f; unsigned u; } v; v.f = f;
    unsigned r = (v.u + 0x7FFFu + ((v.u >> 16) & 1u)) >> 16;
    return (short)r;
}

__device__ __forceinline__ float gelu_f(float x) {
    // tanh-approximate gelu, matches jax.nn.gelu(approximate=True)
    float u = 0.7978845608028654f * (x + 0.044715f * x * x * x);
    float e = __expf(2.0f * u);
    return 0.5f * x * (2.0f - 2.0f / (e + 1.0f));   // 0.5x(1+tanh(u)), overflow-safe
}

// ---------------------------------------------------------------------------
// Kernel 1: LayerNorm + gate logits (fp64 accum) + coef logits, per token row.
// ---------------------------------------------------------------------------
__global__ __launch_bounds__(256) void ln_gate_kernel(
    const float* __restrict__ x, const float* __restrict__ nw, const float* __restrict__ nb,
    const float* __restrict__ wg, const float* __restrict__ rcf,
    short* __restrict__ attn_bf, int* __restrict__ eidx, float* __restrict__ gate,
    float* __restrict__ coef0, float* __restrict__ coef1)
{
    int s = blockIdx.x, tid = threadIdx.x;
    __shared__ float red[256], red2[256];
    __shared__ double redg[10 * 256];

    float4 xv = *(const float4*)(x + (size_t)s * HID + tid * 4);
    float sum = xv.x + xv.y + xv.z + xv.w;
    float sq  = xv.x*xv.x + xv.y*xv.y + xv.z*xv.z + xv.w*xv.w;
    red[tid] = sum; red2[tid] = sq;
    __syncthreads();
    for (int off = 128; off > 0; off >>= 1) {
        if (tid < off) { red[tid] += red[tid + off]; red2[tid] += red2[tid + off]; }
        __syncthreads();
    }
    float m  = red[0] * (1.0f / HID);
    float var = red2[0] * (1.0f / HID) - m * m;
    float rs = rsqrtf(var + 1e-12f);

    float4 g4 = *(const float4*)(nw + tid * 4);
    float4 b4 = *(const float4*)(nb + tid * 4);
    float y[4];
    y[0] = (xv.x - m) * rs * g4.x + b4.x;
    y[1] = (xv.y - m) * rs * g4.y + b4.y;
    y[2] = (xv.z - m) * rs * g4.z + b4.z;
    y[3] = (xv.w - m) * rs * g4.w + b4.w;

    short4 yb = { f2bf(y[0]), f2bf(y[1]), f2bf(y[2]), f2bf(y[3]) };
    *(short4*)(attn_bf + (size_t)s * HID + tid * 4) = yb;

    double a[10];
#pragma unroll
    for (int q = 0; q < 10; q++) a[q] = 0.0;
#pragma unroll
    for (int j = 0; j < 4; j++) {
        int k = tid * 4 + j;
        float4 w0 = *(const float4*)(wg + k * 8);
        float4 w1 = *(const float4*)(wg + k * 8 + 4);
        double yj = (double)y[j];
        a[0] += yj * w0.x; a[1] += yj * w0.y; a[2] += yj * w0.z; a[3] += yj * w0.w;
        a[4] += yj * w1.x; a[5] += yj * w1.y; a[6] += yj * w1.z; a[7] += yj * w1.w;
        float2 rc = *(const float2*)(rcf + k * 2);
        a[8] += yj * rc.x; a[9] += yj * rc.y;
    }
#pragma unroll
    for (int q = 0; q < 10; q++) redg[q * 256 + tid] = a[q];
    __syncthreads();
    for (int off = 128; off > 0; off >>= 1) {
        if (tid < off) {
#pragma unroll
            for (int q = 0; q < 10; q++) redg[q * 256 + tid] += redg[q * 256 + tid + off];
        }
        __syncthreads();
    }
    if (tid == 0) {
        float l[8];
#pragma unroll
        for (int e = 0; e < 8; e++) l[e] = (float)redg[e * 256];
        int bi = 0; float bv = l[0];
#pragma unroll
        for (int e = 1; e < 8; e++) if (l[e] > bv) { bv = l[e]; bi = e; }
        float den = 0.0f;
#pragma unroll
        for (int e = 0; e < 8; e++) den += expf(l[e] - bv);
        gate[s] = 1.0f / den;          // softmax prob of argmax expert
        eidx[s] = bi;
        float r0 = (float)redg[8 * 256], r1 = (float)redg[9 * 256];
        float mx = fmaxf(r0, r1);
        float e0 = expf(r0 - mx), e1 = expf(r1 - mx);
        float inv = 1.0f / (e0 + e1);
        coef0[s] = e0 * inv; coef1[s] = e1 * inv;
    }
}

// ---------------------------------------------------------------------------
// Kernel 2: capacity assignment — exclusive cumsum per expert in token order.
// Single block; each thread owns 32 consecutive tokens; block-wide scan.
// ---------------------------------------------------------------------------
__global__ __launch_bounds__(256) void assign_kernel(
    const int* __restrict__ eidx, int* __restrict__ slot, int* __restrict__ map)
{
    int tid = threadIdx.x;
    for (int i = tid; i < NEXP * CAPX; i += 256) map[i] = -1;

    __shared__ int cnt[2][256][NEXP];   // 16 KiB
    int c[NEXP];
#pragma unroll
    for (int e = 0; e < NEXP; e++) c[e] = 0;
    int base = tid * 32;
    for (int t = 0; t < 32; t++) { int e = eidx[base + t]; c[e]++; }
#pragma unroll
    for (int e = 0; e < NEXP; e++) cnt[0][tid][e] = c[e];
    __syncthreads();

    int src = 0;
    for (int step = 1; step < 256; step <<= 1) {
        int dst = src ^ 1;
#pragma unroll
        for (int e = 0; e < NEXP; e++) {
            int v = cnt[src][tid][e];
            if (tid >= step) v += cnt[src][tid - step][e];
            cnt[dst][tid][e] = v;
        }
        __syncthreads();
        src = dst;
    }
    int off[NEXP];
#pragma unroll
    for (int e = 0; e < NEXP; e++) off[e] = (tid > 0) ? cnt[src][tid - 1][e] : 0;
    for (int t = 0; t < 32; t++) {
        int s = base + t;
        int e = eidx[s];
        int loc = off[e]++;          // counts ALL tokens (ref cumsum ignores drops)
        if (loc < CAPX) { slot[s] = loc; map[e * CAPX + loc] = s; }
        else            { slot[s] = -1; }
    }
}

// ---------------------------------------------------------------------------
// Kernel 3: dispatch gather -> dispatched[e,c,:] bf16 (zeros for empty slots)
// ---------------------------------------------------------------------------
__global__ __launch_bounds__(256) void gather_kernel(
    const int* __restrict__ map, const short* __restrict__ attn_bf, short* __restrict__ disp)
{
    int row = blockIdx.x, tid = threadIdx.x;
    int s = map[row];
    short4 v = { 0, 0, 0, 0 };
    if (s >= 0) v = *(const short4*)(attn_bf + (size_t)s * HID + tid * 4);
    *(short4*)(disp + (size_t)row * HID + tid * 4) = v;
}

// ---------------------------------------------------------------------------
// GEMM: out[M,N] = act(A[M,K](bf16) @ W[K,N](fp32->bf16 inline) + bias[N])
// 128x128 tile, 4 waves (2x2), each wave 4x4 of 16x16x32 MFMA. Batch via z.
// ---------------------------------------------------------------------------
template<int ACT, typename OUT_T>
__global__ __launch_bounds__(256) void gemm_kernel(
    const short* __restrict__ A, const float* __restrict__ W,
    const float* __restrict__ bias, OUT_T* __restrict__ out,
    int N, int K, long sA, long sW, long sB, long sO)
{
    constexpr int PITCH = 72;          // 144B row pitch: frag reads at 8-cycle minimum
    __shared__ __align__(16) short a_lds[128 * PITCH];
    __shared__ __align__(16) short b_lds[128 * PITCH];

    long b = blockIdx.z;
    const short* Ab = A + b * sA;
    const float* Wb = W + b * sW + blockIdx.x * 128;
    const float* biasb = bias + b * sB;
    OUT_T* outb = out + b * sO;

    int tid = threadIdx.x;
    int lane = tid & 63, wave = tid >> 6;
    int wm = wave & 1, wn = wave >> 1;
    int lm = lane & 15, lq = lane >> 4;

    const short* Ablk = Ab + (long)blockIdx.y * 128 * K;

    f32x4 acc[4][4];
#pragma unroll
    for (int i = 0; i < 4; i++)
#pragma unroll
        for (int j = 0; j < 4; j++) acc[i][j] = { 0.f, 0.f, 0.f, 0.f };

    for (int kb = 0; kb < K; kb += 64) {
        __syncthreads();
        // stage A tile: 128 rows x 64 k (bf16 already)
#pragma unroll
        for (int it = 0; it < 4; it++) {
            int slot = it * 256 + tid;
            int row = slot >> 3, ch = slot & 7;
            int4 v = *(const int4*)(Ablk + (long)row * K + kb + ch * 8);
            *(int4*)(a_lds + row * PITCH + ch * 8) = v;
        }
        // stage W tile: 64 k x 128 n, fp32 -> bf16, transposed into [n][k]
#pragma unroll
        for (int it = 0; it < 8; it++) {
            int slot = it * 256 + tid;
            int n = slot & 127, kq = slot >> 7;
            int k = kq * 4;
            const float* wp = Wb + (long)(kb + k) * N + n;
            float w0 = wp[0], w1 = wp[N], w2 = wp[2 * (long)N], w3 = wp[3 * (long)N];
            int lo = (f2bf(w0) & 0xFFFF) | (f2bf(w1) << 16);
            int hi = (f2bf(w2) & 0xFFFF) | (f2bf(w3) << 16);
            int2 pk; pk.x = lo; pk.y = hi;
            *(int2*)(b_lds + n * PITCH + k) = pk;
        }
        __syncthreads();
#pragma unroll
        for (int ks = 0; ks < 64; ks += 32) {
            bf16x8 af[4], bfr[4];
#pragma unroll
            for (int i = 0; i < 4; i++)
                af[i] = *(const bf16x8*)(a_lds + (wm * 64 + i * 16 + lm) * PITCH + ks + lq * 8);
#pragma unroll
            for (int j = 0; j < 4; j++)
                bfr[j] = *(const bf16x8*)(b_lds + (wn * 64 + j * 16 + lm) * PITCH + ks + lq * 8);
#pragma unroll
            for (int i = 0; i < 4; i++)
#pragma unroll
                for (int j = 0; j < 4; j++)
                    acc[i][j] = __builtin_amdgcn_mfma_f32_16x16x32_bf16(af[i], bfr[j], acc[i][j], 0, 0, 0);
        }
    }

    // epilogue: C/D layout col=lane&15, row=(lane>>4)*4+r
#pragma unroll
    for (int j = 0; j < 4; j++) {
        int col = blockIdx.x * 128 + wn * 64 + j * 16 + lm;
        float bb = biasb[col];
#pragma unroll
        for (int i = 0; i < 4; i++) {
#pragma unroll
            for (int r = 0; r < 4; r++) {
                int row = blockIdx.y * 128 + wm * 64 + i * 16 + lq * 4 + r;
                float v = acc[i][j][r] + bb;
                if (ACT) v = gelu_f(v);
                if constexpr (std::is_same_v<OUT_T, short>)
                    outb[(long)row * N + col] = f2bf(v);
                else
                    outb[(long)row * N + col] = v;
            }
        }
    }
}

// ---------------------------------------------------------------------------
// Kernel 5: final combine: out = res_mlp*c0 + gate*expert_out*c1 + residual
// ---------------------------------------------------------------------------
__global__ __launch_bounds__(256) void final_kernel(
    const float* __restrict__ x, const float* __restrict__ res_mlp,
    const float* __restrict__ eout, const int* __restrict__ eidx,
    const int* __restrict__ slot, const float* __restrict__ gate,
    const float* __restrict__ coef0, const float* __restrict__ coef1,
    float* __restrict__ out)
{
    int s = blockIdx.x, tid = threadIdx.x;
    float c0 = coef0[s], c1 = coef1[s];
    int sl = slot[s];
    float g = gate[s] * c1;
    int e = eidx[s];
    float4 r  = *(const float4*)(x + (size_t)s * HID + tid * 4);
    float4 rm = *(const float4*)(res_mlp + (size_t)s * HID + tid * 4);
    float4 mo = { 0.f, 0.f, 0.f, 0.f };
    if (sl >= 0) mo = *(const float4*)(eout + ((size_t)(e * CAPX + sl)) * HID + tid * 4);
    float4 o;
    o.x = rm.x * c0 + g * mo.x + r.x;
    o.y = rm.y * c0 + g * mo.y + r.y;
    o.z = rm.z * c0 + g * mo.z + r.z;
    o.w = rm.w * c0 + g * mo.w + r.w;
    *(float4*)(out + (size_t)s * HID + tid * 4) = o;
}

extern "C" void kernel_launch(void* const* d_in, const int* in_sizes, int n_in,
                              void* d_out, int out_size, void* d_ws, size_t ws_size,
                              hipStream_t stream) {
    const float* x           = (const float*)d_in[0];
    const float* attn_nw     = (const float*)d_in[1];
    const float* attn_nb     = (const float*)d_in[2];
    const float* wg          = (const float*)d_in[3];
    const float* inter_w     = (const float*)d_in[4];
    const float* inter_b     = (const float*)d_in[5];
    const float* output_w    = (const float*)d_in[6];
    const float* output_b    = (const float*)d_in[7];
    const float* res_inter_w = (const float*)d_in[8];
    const float* res_inter_b = (const float*)d_in[9];
    const float* res_output_w= (const float*)d_in[10];
    const float* res_output_b= (const float*)d_in[11];
    const float* res_coef    = (const float*)d_in[12];
    float* out = (float*)d_out;

    char* ws = (char*)d_ws;
    size_t off = 0;
    auto alloc = [&](size_t bytes) { void* p = ws + off; off += (bytes + 255) & ~(size_t)255; return p; };
    short* attn_bf = (short*)alloc((size_t)S_TOK * HID * 2);          // 16 MiB
    short* disp    = (short*)alloc((size_t)NEXP * CAPX * HID * 2);    // 16 MiB
    short* hbuf    = (short*)alloc((size_t)NEXP * CAPX * INTERX * 2); // 64 MiB (h, then rh)
    float* eout    = (float*)alloc((size_t)NEXP * CAPX * HID * 4);    // 32 MiB
    float* resmlp  = (float*)alloc((size_t)S_TOK * HID * 4);          // 32 MiB
    int*   eidx    = (int*)alloc(S_TOK * 4);
    int*   slot    = (int*)alloc(S_TOK * 4);
    float* gate    = (float*)alloc(S_TOK * 4);
    float* c0      = (float*)alloc(S_TOK * 4);
    float* c1      = (float*)alloc(S_TOK * 4);
    int*   map     = (int*)alloc(NEXP * CAPX * 4);

    ln_gate_kernel<<<S_TOK, 256, 0, stream>>>(x, attn_nw, attn_nb, wg, res_coef,
                                              attn_bf, eidx, gate, c0, c1);
    assign_kernel<<<1, 256, 0, stream>>>(eidx, slot, map);
    gather_kernel<<<NEXP * CAPX, 256, 0, stream>>>(map, attn_bf, disp);

    // expert GEMM1: [8][1024,1024] @ [1024,4096] -> gelu -> h (bf16)
    dim3 g1(INTERX / 128, CAPX / 128, NEXP);
    gemm_kernel<1, short><<<g1, 256, 0, stream>>>(
        disp, inter_w, inter_b, hbuf, INTERX, HID,
        (long)CAPX * HID, (long)HID * INTERX, INTERX, (long)CAPX * INTERX);
    // expert GEMM2: [8][1024,4096] @ [4096,1024] -> expert_out (f32)
    dim3 g2(HID / 128, CAPX / 128, NEXP);
    gemm_kernel<0, float><<<g2, 256, 0, stream>>>(
        hbuf, output_w, output_b, eout, HID, INTERX,
        (long)CAPX * INTERX, (long)INTERX * HID, HID, (long)CAPX * HID);
    // residual GEMM1: [8192,1024] @ [1024,4096] -> gelu -> rh (bf16, reuse hbuf)
    dim3 g3(INTERX / 128, S_TOK / 128, 1);
    gemm_kernel<1, short><<<g3, 256, 0, stream>>>(
        attn_bf, res_inter_w, res_inter_b, hbuf, INTERX, HID, 0, 0, 0, 0);
    // residual GEMM2: [8192,4096] @ [4096,1024] -> res_mlp (f32)
    dim3 g4(HID / 128, S_TOK / 128, 1);
    gemm_kernel<0, float><<<g4, 256, 0, stream>>>(
        hbuf, res_output_w, res_output_b, resmlp, HID, INTERX, 0, 0, 0, 0);

    final_kernel<<<S_TOK, 256, 0, stream>>>(x, resmlp, eout, eidx, slot, gate, c0, c1, out);

    (void)in_sizes; (void)n_in; (void)out_size; (void)ws_size;
}